// Round 3
// baseline (144.077 us; speedup 1.0000x reference)
//
#include <hip/hip_runtime.h>
#include <hip/hip_bf16.h>

typedef __bf16 bf16x8 __attribute__((ext_vector_type(8)));
typedef float  f32x4  __attribute__((ext_vector_type(4)));

#define VOCAB 24
#define EDIM  16
#define HDIM  32
#define TLEN  128

__device__ __forceinline__ float xor8f(float v) {
    // lane <- lane^8 within each 16-lane row (row_ror:8; VALU DPP, no LDS)
    int r = __builtin_amdgcn_update_dpp(0, __float_as_int(v), 0x128, 0xF, 0xF, true);
    return __int_as_float(r);
}
__device__ __forceinline__ float fast_sig(float x) {
    float t = __builtin_amdgcn_exp2f(x * -1.44269504f);
    return __builtin_amdgcn_rcpf(1.0f + t);
}
__device__ __forceinline__ float fast_tanh(float x) {
    float t = __builtin_amdgcn_exp2f(x * -2.88539008f);
    return __builtin_amdgcn_rcpf(1.0f + t) * 2.0f - 1.0f;
}

// Block = 4 waves, one 16-row batch group. Wave w owns hidden units
// j in [8w, 8w+8). Permuted-column MFMA tiles:
//   tile p, col n  ->  gate q = 2p + (n>>3), hidden j = 8w + (n&7)
// so tile0 = {i|f}, tile1 = {g|o} for this wave's 8 hidden units. After the
// MFMAs, each lane holds 2 of the 4 gates of hidden j=8w+(l15&7) for rows
// 4hi..4hi+3; the other 2 live at lane^8 and are fetched with DPP row_ror:8.
// Low lanes (l15<8) update rows 4hi+{0,1}, high lanes rows 4hi+{2,3}
// (2 elements / lane, c in registers). Only h goes through LDS; 1 barrier/step.
__global__ __launch_bounds__(256, 4) void lstm_fused(
    const int*   __restrict__ x,     // [B][128]
    const float* __restrict__ emb,   // [24][16]
    const float* __restrict__ W_ih,  // [128][16]
    const float* __restrict__ W_hh,  // [128][32]
    const float* __restrict__ b_ih,  // [128]
    const float* __restrict__ b_hh,  // [128]
    const float* __restrict__ fc_w,  // [2][32]
    const float* __restrict__ fc_b,  // [2]
    float*       __restrict__ out)   // [B][2]
{
    __shared__ __align__(16) __bf16 hbuf[2][16][40];  // h double-buffer, 80B rows
    __shared__ __align__(16) float  fbuf[16][33];     // final h (f32) for FC

    const int tid   = threadIdx.x;
    const int wid   = tid >> 6;          // 0..3 : hidden-unit octet
    const int lane  = tid & 63;
    const int l15   = lane & 15;
    const int hi    = lane >> 4;         // 0..3
    const int kbase = hi * 8;
    const int row0  = blockIdx.x * 16;
    const bool lowj = (l15 < 8);
    const int  j    = wid * 8 + (l15 & 7);   // this lane's hidden unit

    // ---- B-fragments (permuted gate columns), kept in registers ----
    bf16x8 b1f[2];  // W_hh^T : B1[k][gcol] = W_hh[gcol][k]
    bf16x8 b2f[2];  // table  : B2[v][gcol] = emb[v].W_ih[gcol] + b_ih+b_hh
    #pragma unroll
    for (int p = 0; p < 2; ++p) {
        const int gcol = (2 * p + (l15 >> 3)) * 32 + j;
        const float* wrow = W_hh + gcol * HDIM;
        #pragma unroll
        for (int i = 0; i < 8; ++i)
            b1f[p][i] = (__bf16)wrow[kbase + i];
        const float bias = b_ih[gcol] + b_hh[gcol];
        const float* wi = W_ih + gcol * EDIM;
        #pragma unroll
        for (int i = 0; i < 8; ++i) {
            const int v = kbase + i;
            float s = 0.0f;
            if (v < VOCAB) {
                s = bias;
                #pragma unroll
                for (int e = 0; e < EDIM; ++e)
                    s += emb[v * EDIM + e] * wi[e];
            }
            b2f[p][i] = (__bf16)s;
        }
    }

    // tile1 activation constants: g (low lanes) -> tanh, o (high) -> sigmoid
    const float k1  = lowj ? -2.88539008f : -1.44269504f;
    const float a1c = lowj ?  2.0f : 1.0f;
    const float b1c = lowj ? -1.0f : 0.0f;
    const int   rr  = lowj ? 0 : 2;      // first owned acc row

    float c0 = 0.0f, c1 = 0.0f;
    const int* xrow = x + (row0 + l15) * TLEN;   // A-row of this lane = l15

    int4 xq;
    for (int t = 0; t < TLEN; ++t) {
        if ((t & 3) == 0) xq = *(const int4*)(xrow + t);
        const int xv = (t & 1) ? ((t & 2) ? xq.w : xq.y)
                               : ((t & 2) ? xq.z : xq.x);

        // one-hot A2: A2[row=l15][k] = (k == x[row][t])
        bf16x8 a2;
        #pragma unroll
        for (int i = 0; i < 8; ++i)
            a2[i] = (kbase + i == xv) ? (__bf16)1.0f : (__bf16)0.0f;

        const f32x4 z = {0.f, 0.f, 0.f, 0.f};
        f32x4 acc0 = __builtin_amdgcn_mfma_f32_16x16x32_bf16(a2, b2f[0], z, 0, 0, 0);
        f32x4 acc1 = __builtin_amdgcn_mfma_f32_16x16x32_bf16(a2, b2f[1], z, 0, 0, 0);
        if (t > 0) {   // uniform; hbuf[(t-1)&1] ready since barrier of step t-1
            const bf16x8 a1v = *(const bf16x8*)&hbuf[(t - 1) & 1][l15][kbase];
            acc0 = __builtin_amdgcn_mfma_f32_16x16x32_bf16(a1v, b1f[0], acc0, 0, 0, 0);
            acc1 = __builtin_amdgcn_mfma_f32_16x16x32_bf16(a1v, b1f[1], acc1, 0, 0, 0);
        }

        // ---- activations (tile0: pure sigmoid; tile1: per-lane const) ----
        float s0[4], s1[4], x0[4], x1[4];
        #pragma unroll
        for (int r = 0; r < 4; ++r) {
            s0[r] = fast_sig(acc0[r]);
            const float u = __builtin_amdgcn_exp2f(acc1[r] * k1);
            s1[r] = fmaf(a1c, __builtin_amdgcn_rcpf(1.0f + u), b1c);
        }
        #pragma unroll
        for (int r = 0; r < 4; ++r) { x0[r] = xor8f(s0[r]); x1[r] = xor8f(s1[r]); }

        // ---- 2 elements per lane: rows 4hi+rr+{0,1}, hidden j ----
        // low lane locals: i (s0), g (s1); partners f (x0), o (x1). High: swapped.
        float hv0, hv1;
        {
            const float iv = lowj ? s0[0] : x0[2];
            const float fv = lowj ? x0[0] : s0[2];
            const float gv = lowj ? s1[0] : x1[2];
            const float ov = lowj ? x1[0] : s1[2];
            c0 = fv * c0 + iv * gv;
            hv0 = ov * fast_tanh(c0);
        }
        {
            const float iv = lowj ? s0[1] : x0[3];
            const float fv = lowj ? x0[1] : s0[3];
            const float gv = lowj ? s1[1] : x1[3];
            const float ov = lowj ? x1[1] : s1[3];
            c1 = fv * c1 + iv * gv;
            hv1 = ov * fast_tanh(c1);
        }

        const int row = 4 * hi + rr;
        hbuf[t & 1][row    ][j] = (__bf16)hv0;
        hbuf[t & 1][row + 1][j] = (__bf16)hv1;
        if (t == TLEN - 1) {
            fbuf[row    ][j] = hv0;
            fbuf[row + 1][j] = hv1;
        }
        __syncthreads();   // h of step t visible; buffers alternate -> 1 barrier/step
    }

    // ---- FC epilogue: out[b] = h_last[b] @ fc_w^T + fc_b ----
    if (tid < 16) {
        float o0 = fc_b[0], o1 = fc_b[1];
        #pragma unroll
        for (int jj = 0; jj < HDIM; ++jj) {
            const float h = fbuf[tid][jj];
            o0 += fc_w[jj]        * h;
            o1 += fc_w[HDIM + jj] * h;
        }
        float2 res;
        res.x = o0; res.y = o1;
        *(float2*)&out[(row0 + tid) * 2] = res;
    }
}

extern "C" void kernel_launch(void* const* d_in, const int* in_sizes, int n_in,
                              void* d_out, int out_size, void* d_ws, size_t ws_size,
                              hipStream_t stream) {
    const int*   x    = (const int*)  d_in[0];
    const float* emb  = (const float*)d_in[1];
    const float* W_ih = (const float*)d_in[2];
    const float* W_hh = (const float*)d_in[3];
    const float* b_ih = (const float*)d_in[4];
    const float* b_hh = (const float*)d_in[5];
    const float* fc_w = (const float*)d_in[6];
    const float* fc_b = (const float*)d_in[7];
    float* out = (float*)d_out;

    const int B    = in_sizes[0] / TLEN;   // 16384
    const int nblk = B / 16;               // 1024 blocks x 4 waves

    lstm_fused<<<nblk, 256, 0, stream>>>(x, emb, W_ih, W_hh, b_ih, b_hh, fc_w, fc_b, out);
}

// Round 5
// 132.262 us; speedup vs baseline: 1.0893x; 1.0893x over previous
//
#include <hip/hip_runtime.h>
#include <hip/hip_bf16.h>

typedef __bf16 bf16x8 __attribute__((ext_vector_type(8)));
typedef float  f32x4  __attribute__((ext_vector_type(4)));

#define VOCAB 24
#define EDIM  16
#define HDIM  32
#define TLEN  128

union A2U { int4 w; bf16x8 v; };

__device__ __forceinline__ float xor8f(float v) {
    // lane <- lane^8 within each 16-lane row (row_ror:8; VALU DPP, no LDS)
    int r = __builtin_amdgcn_update_dpp(0, __float_as_int(v), 0x128, 0xF, 0xF, true);
    return __int_as_float(r);
}
__device__ __forceinline__ float fast_sig(float x) {
    // sigmoid(x) = 1 / (1 + 2^(-x*log2(e)))   (mul, exp2, add, rcp)
    float t = __builtin_amdgcn_exp2f(x * -1.44269504f);
    return __builtin_amdgcn_rcpf(1.0f + t);
}
__device__ __forceinline__ float fast_tanh(float x) {
    float t = __builtin_amdgcn_exp2f(x * -2.88539008f);
    return __builtin_amdgcn_rcpf(1.0f + t) * 2.0f - 1.0f;
}

// Block = 4 waves, one 16-row batch group. Wave w owns hidden units
// j in [8w, 8w+8). Permuted-column MFMA tiles: tile p, col n ->
// gate q = 2p + (n>>3), hidden j = 8w + (n&7); tile0 = {i|f}, tile1 = {g|o}.
// After MFMA each lane holds 2 of 4 gates of hidden j for its rows; the other
// 2 come from lane^8 via DPP row_ror:8. Low lanes update rows 4hi+{0,1},
// high lanes rows 4hi+{2,3}. Only h crosses waves (LDS), 1 barrier/step.
// t-loop unrolled 4x: all LDS offsets / xv selection / last-step handling are
// compile-time static.
//
// tile1 activation: low lanes need tanh(x) = 2*sig(2x)-1, high lanes sig(x).
//   s1 = fma(a1c, fast_sig(ksig*x), b1c),  ksig = lowj?2:1, a1c = lowj?2:1,
//   b1c = lowj?-1:0.   (R3 bug: an extra *1.44269504 in this argument.)
__global__ __launch_bounds__(256, 4) void lstm_fused(
    const int*   __restrict__ x,     // [B][128]
    const float* __restrict__ emb,   // [24][16]
    const float* __restrict__ W_ih,  // [128][16]
    const float* __restrict__ W_hh,  // [128][32]
    const float* __restrict__ b_ih,  // [128]
    const float* __restrict__ b_hh,  // [128]
    const float* __restrict__ fc_w,  // [2][32]
    const float* __restrict__ fc_b,  // [2]
    float*       __restrict__ out)   // [B][2]
{
    __shared__ __align__(16) __bf16 hbuf[2][16][40];  // h double-buffer, 80B rows
    __shared__ __align__(16) float  fbuf[16][33];     // final h (f32) for FC

    const int tid   = threadIdx.x;
    const int wid   = tid >> 6;
    const int lane  = tid & 63;
    const int l15   = lane & 15;
    const int hi    = lane >> 4;
    const int kbase = hi * 8;
    const int kh    = hi * 4;            // kbase>>1 : packed-word index base
    const int row0  = blockIdx.x * 16;
    const bool lowj = (l15 < 8);
    const int  j    = wid * 8 + (l15 & 7);

    // ---- B-fragments (permuted gate columns), registers ----
    bf16x8 b1f[2];  // W_hh^T
    bf16x8 b2f[2];  // lookup table: emb[v].W_ih[gcol] + b_ih+b_hh
    #pragma unroll
    for (int p = 0; p < 2; ++p) {
        const int gcol = (2 * p + (l15 >> 3)) * 32 + j;
        const float* wrow = W_hh + gcol * HDIM;
        #pragma unroll
        for (int i = 0; i < 8; ++i)
            b1f[p][i] = (__bf16)wrow[kbase + i];
        const float bias = b_ih[gcol] + b_hh[gcol];
        const float* wi = W_ih + gcol * EDIM;
        #pragma unroll
        for (int i = 0; i < 8; ++i) {
            const int v = kbase + i;
            float s = 0.0f;
            if (v < VOCAB) {
                s = bias;
                #pragma unroll
                for (int e = 0; e < EDIM; ++e)
                    s += emb[v * EDIM + e] * wi[e];
            }
            b2f[p][i] = (__bf16)s;
        }
    }

    // tile1 activation constants: g (low lanes) -> tanh, o (high) -> sigmoid
    const float ksig = lowj ?  2.0f : 1.0f;
    const float a1c  = lowj ?  2.0f : 1.0f;
    const float b1c  = lowj ? -1.0f : 0.0f;
    const int   urow = 4 * hi + (lowj ? 0 : 2);   // first owned row

    float c0 = 0.0f, c1 = 0.0f;
    const int* xrow = x + (row0 + l15) * TLEN;
    const f32x4 z = {0.f, 0.f, 0.f, 0.f};

    int4 xq = *(const int4*)xrow;   // words for t = 0..3

// One LSTM step. P = t&1 (compile-time), XV = token, FIRST skips the h-MFMA,
// LAST routes h to fbuf (f32) instead of hbuf.
#define SLOT(XV, P, FIRST, LAST) do {                                          \
    const int xv_   = (XV);                                                    \
    const int hotw_ = 0x3F80 << ((xv_ & 1) << 4);                              \
    const int hoth_ = xv_ >> 1;                                                \
    A2U a2u_;                                                                  \
    a2u_.w.x = (hoth_ == kh + 0) ? hotw_ : 0;                                  \
    a2u_.w.y = (hoth_ == kh + 1) ? hotw_ : 0;                                  \
    a2u_.w.z = (hoth_ == kh + 2) ? hotw_ : 0;                                  \
    a2u_.w.w = (hoth_ == kh + 3) ? hotw_ : 0;                                  \
    f32x4 acc0_ = __builtin_amdgcn_mfma_f32_16x16x32_bf16(a2u_.v, b2f[0], z, 0, 0, 0); \
    f32x4 acc1_ = __builtin_amdgcn_mfma_f32_16x16x32_bf16(a2u_.v, b2f[1], z, 0, 0, 0); \
    if (!(FIRST)) {                                                            \
        const bf16x8 a1v_ = *(const bf16x8*)&hbuf[(P) ^ 1][l15][kbase];        \
        acc0_ = __builtin_amdgcn_mfma_f32_16x16x32_bf16(a1v_, b1f[0], acc0_, 0, 0, 0); \
        acc1_ = __builtin_amdgcn_mfma_f32_16x16x32_bf16(a1v_, b1f[1], acc1_, 0, 0, 0); \
    }                                                                          \
    const float s00_ = fast_sig(acc0_[0]);                                     \
    const float s01_ = fast_sig(acc0_[1]);                                     \
    const float s02_ = fast_sig(acc0_[2]);                                     \
    const float s03_ = fast_sig(acc0_[3]);                                     \
    const float s10_ = fmaf(a1c, fast_sig(acc1_[0] * ksig), b1c);              \
    const float s11_ = fmaf(a1c, fast_sig(acc1_[1] * ksig), b1c);              \
    const float s12_ = fmaf(a1c, fast_sig(acc1_[2] * ksig), b1c);              \
    const float s13_ = fmaf(a1c, fast_sig(acc1_[3] * ksig), b1c);              \
    const float x00_ = xor8f(s00_), x01_ = xor8f(s01_);                        \
    const float x02_ = xor8f(s02_), x03_ = xor8f(s03_);                        \
    const float x10_ = xor8f(s10_), x11_ = xor8f(s11_);                        \
    const float x12_ = xor8f(s12_), x13_ = xor8f(s13_);                        \
    const float iv0_ = lowj ? s00_ : x02_;                                     \
    const float fv0_ = lowj ? x00_ : s02_;                                     \
    const float gv0_ = lowj ? s10_ : x12_;                                     \
    const float ov0_ = lowj ? x10_ : s12_;                                     \
    c0 = fmaf(fv0_, c0, iv0_ * gv0_);                                          \
    const float hv0_ = ov0_ * fast_tanh(c0);                                   \
    const float iv1_ = lowj ? s01_ : x03_;                                     \
    const float fv1_ = lowj ? x01_ : s03_;                                     \
    const float gv1_ = lowj ? s11_ : x13_;                                     \
    const float ov1_ = lowj ? x11_ : s13_;                                     \
    c1 = fmaf(fv1_, c1, iv1_ * gv1_);                                          \
    const float hv1_ = ov1_ * fast_tanh(c1);                                   \
    if (!(LAST)) {                                                             \
        hbuf[P][urow    ][j] = (__bf16)hv0_;                                   \
        hbuf[P][urow + 1][j] = (__bf16)hv1_;                                   \
    } else {                                                                   \
        fbuf[urow    ][j] = hv0_;                                              \
        fbuf[urow + 1][j] = hv1_;                                              \
    }                                                                          \
    __syncthreads();                                                           \
} while (0)

    // t = 0 (no h yet)
    SLOT(xq.x, 0, true, false);

    // t = 1 .. 124, four steps per iteration (parities static)
    #pragma unroll 1
    for (int t = 1; t < 125; t += 4) {
        SLOT(xq.y, 1, false, false);           // t
        SLOT(xq.z, 0, false, false);           // t+1
        SLOT(xq.w, 1, false, false);           // t+2
        xq = *(const int4*)(xrow + t + 3);     // words t+3 .. t+6
        SLOT(xq.x, 0, false, false);           // t+3
    }

    // t = 125, 126, 127
    SLOT(xq.y, 1, false, false);
    SLOT(xq.z, 0, false, false);
    SLOT(xq.w, 1, false, true);                // h -> fbuf (f32)

#undef SLOT

    // ---- FC epilogue: out[b] = h_last[b] @ fc_w^T + fc_b ----
    if (tid < 16) {
        float o0 = fc_b[0], o1 = fc_b[1];
        #pragma unroll
        for (int jj = 0; jj < HDIM; ++jj) {
            const float h = fbuf[tid][jj];
            o0 += fc_w[jj]        * h;
            o1 += fc_w[HDIM + jj] * h;
        }
        float2 res;
        res.x = o0; res.y = o1;
        *(float2*)&out[(row0 + tid) * 2] = res;
    }
}

extern "C" void kernel_launch(void* const* d_in, const int* in_sizes, int n_in,
                              void* d_out, int out_size, void* d_ws, size_t ws_size,
                              hipStream_t stream) {
    const int*   x    = (const int*)  d_in[0];
    const float* emb  = (const float*)d_in[1];
    const float* W_ih = (const float*)d_in[2];
    const float* W_hh = (const float*)d_in[3];
    const float* b_ih = (const float*)d_in[4];
    const float* b_hh = (const float*)d_in[5];
    const float* fc_w = (const float*)d_in[6];
    const float* fc_b = (const float*)d_in[7];
    float* out = (float*)d_out;

    const int B    = in_sizes[0] / TLEN;   // 16384
    const int nblk = B / 16;               // 1024 blocks x 4 waves

    lstm_fused<<<nblk, 256, 0, stream>>>(x, emb, W_ih, W_hh, b_ih, b_hh, fc_w, fc_b, out);
}

// Round 6
// 120.721 us; speedup vs baseline: 1.1935x; 1.0956x over previous
//
#include <hip/hip_runtime.h>
#include <hip/hip_bf16.h>

typedef __bf16 bf16x8 __attribute__((ext_vector_type(8)));
typedef float  f32x4  __attribute__((ext_vector_type(4)));

#define VOCAB 24
#define EDIM  16
#define HDIM  32
#define TLEN  128

union A2U { int4 w; bf16x8 v; };

__device__ __forceinline__ float xor8f(float v) {
    // lane <- lane^8 within each 16-lane row (row_ror:8; VALU DPP, no LDS)
    int r = __builtin_amdgcn_update_dpp(0, __float_as_int(v), 0x128, 0xF, 0xF, true);
    return __int_as_float(r);
}
// B-matrices are pre-scaled by -log2(e) (sigmoid cols) / -2*log2(e) (tanh
// cols), so gate activations need no multiply:
__device__ __forceinline__ float rsig(float a) {   // sigmoid from scaled acc
    return __builtin_amdgcn_rcpf(1.0f + __builtin_amdgcn_exp2f(a));
}
__device__ __forceinline__ float fast_tanh(float x) {
    float t = __builtin_amdgcn_exp2f(x * -2.88539008f);
    return fmaf(2.0f, __builtin_amdgcn_rcpf(1.0f + t), -1.0f);
}

// Block = 4 waves, TWO independent 16-row batch groups (A: rows 0-15,
// B: rows 16-31 of the block). Wave w owns hidden units j in [8w,8w+8) for
// both groups; W_hh / gate-table B-fragments are shared. Per timestep each
// wave runs both groups' MFMA+activation chains back-to-back (independent
// ILP) and ONE barrier covers both groups' h-writes.
// Permuted-column MFMA tiles: tile p, col n -> gate q = 2p + (n>>3),
// hidden j = 8w + (n&7); tile0 = {i|f}, tile1 = {g|o}. After MFMA each lane
// holds 2 of 4 gates of hidden j for its rows; the other 2 come from lane^8
// via DPP row_ror:8. Low lanes update rows 4hi+{0,1}, high lanes 4hi+{2,3}.
__global__ __launch_bounds__(256, 2) void lstm_fused(
    const int*   __restrict__ x,     // [B][128]
    const float* __restrict__ emb,   // [24][16]
    const float* __restrict__ W_ih,  // [128][16]
    const float* __restrict__ W_hh,  // [128][32]
    const float* __restrict__ b_ih,  // [128]
    const float* __restrict__ b_hh,  // [128]
    const float* __restrict__ fc_w,  // [2][32]
    const float* __restrict__ fc_b,  // [2]
    float*       __restrict__ out)   // [B][2]
{
    __shared__ __align__(16) __bf16 hbuf[2][32][40];  // h dbuf, rows 0-15=A,16-31=B
    __shared__ __align__(16) float  fbuf[32][33];     // final h (f32) for FC

    const int tid   = threadIdx.x;
    const int wid   = tid >> 6;
    const int lane  = tid & 63;
    const int l15   = lane & 15;
    const int hi    = lane >> 4;
    const int kbase = hi * 8;
    const int kh    = hi * 4;            // packed-word index base
    const int row0  = blockIdx.x * 32;
    const bool lowj = (l15 < 8);
    const int  j    = wid * 8 + (l15 & 7);

    // ---- B-fragments (permuted gate columns), pre-scaled, registers ----
    bf16x8 b1f[2];  // scale * W_hh^T
    bf16x8 b2f[2];  // scale * (emb[v].W_ih[gcol] + b_ih+b_hh)
    #pragma unroll
    for (int p = 0; p < 2; ++p) {
        const int q    = 2 * p + (l15 >> 3);          // gate id of my column
        const int gcol = q * 32 + j;
        const float scale = (q == 2) ? -2.88539008f : -1.44269504f;
        const float* wrow = W_hh + gcol * HDIM;
        #pragma unroll
        for (int i = 0; i < 8; ++i)
            b1f[p][i] = (__bf16)(scale * wrow[kbase + i]);
        const float bias = b_ih[gcol] + b_hh[gcol];
        const float* wi = W_ih + gcol * EDIM;
        #pragma unroll
        for (int i = 0; i < 8; ++i) {
            const int v = kbase + i;
            float s = 0.0f;
            if (v < VOCAB) {
                s = bias;
                #pragma unroll
                for (int e = 0; e < EDIM; ++e)
                    s += emb[v * EDIM + e] * wi[e];
            }
            b2f[p][i] = (__bf16)(scale * s);
        }
    }

    // tile1 reconstruction consts: g (low lanes) tanh, o (high) sigmoid
    const float a1c  = lowj ?  2.0f : 1.0f;
    const float b1c  = lowj ? -1.0f : 0.0f;
    const int   urow = 4 * hi + (lowj ? 0 : 2);   // first owned row (group A)

    float cA0 = 0.0f, cA1 = 0.0f, cB0 = 0.0f, cB1 = 0.0f;
    const int* xrowA = x + (row0 + l15) * TLEN;
    const int* xrowB = xrowA + 16 * TLEN;
    const f32x4 z = {0.f, 0.f, 0.f, 0.f};

    int4 xqA = *(const int4*)xrowA;   // group A words, t = 0..3
    int4 xqB = *(const int4*)xrowB;   // group B words, t = 0..3

// Build one-hot fragment for token XV.
#define ONEHOT(DST, XV) do {                                                   \
    const int xv_   = (XV);                                                    \
    const int hotw_ = 0x3F80 << ((xv_ & 1) << 4);                              \
    const int hoth_ = xv_ >> 1;                                                \
    DST.w.x = (hoth_ == kh + 0) ? hotw_ : 0;                                   \
    DST.w.y = (hoth_ == kh + 1) ? hotw_ : 0;                                   \
    DST.w.z = (hoth_ == kh + 2) ? hotw_ : 0;                                   \
    DST.w.w = (hoth_ == kh + 3) ? hotw_ : 0;                                   \
} while (0)

// Per-group pointwise update from acc pair -> h values (and c-state update).
#define GUPD(A0, A1, C0, C1, HV0, HV1) do {                                    \
    const float s00_ = rsig(A0[0]), s01_ = rsig(A0[1]);                        \
    const float s02_ = rsig(A0[2]), s03_ = rsig(A0[3]);                        \
    const float s10_ = fmaf(a1c, rsig(A1[0]), b1c);                            \
    const float s11_ = fmaf(a1c, rsig(A1[1]), b1c);                            \
    const float s12_ = fmaf(a1c, rsig(A1[2]), b1c);                            \
    const float s13_ = fmaf(a1c, rsig(A1[3]), b1c);                            \
    const float x00_ = xor8f(s00_), x01_ = xor8f(s01_);                        \
    const float x02_ = xor8f(s02_), x03_ = xor8f(s03_);                        \
    const float x10_ = xor8f(s10_), x11_ = xor8f(s11_);                        \
    const float x12_ = xor8f(s12_), x13_ = xor8f(s13_);                        \
    const float iv0_ = lowj ? s00_ : x02_;                                     \
    const float fv0_ = lowj ? x00_ : s02_;                                     \
    const float gv0_ = lowj ? s10_ : x12_;                                     \
    const float ov0_ = lowj ? x10_ : s12_;                                     \
    C0 = fmaf(fv0_, C0, iv0_ * gv0_);                                          \
    HV0 = ov0_ * fast_tanh(C0);                                                \
    const float iv1_ = lowj ? s01_ : x03_;                                     \
    const float fv1_ = lowj ? x01_ : s03_;                                     \
    const float gv1_ = lowj ? s11_ : x13_;                                     \
    const float ov1_ = lowj ? x11_ : s13_;                                     \
    C1 = fmaf(fv1_, C1, iv1_ * gv1_);                                          \
    HV1 = ov1_ * fast_tanh(C1);                                                \
} while (0)

// One timestep for BOTH groups. P = t&1 (compile-time). One barrier total.
#define SLOT(XVA, XVB, P, FIRST, LAST) do {                                    \
    A2U a2A_, a2B_;                                                            \
    ONEHOT(a2A_, XVA);                                                         \
    ONEHOT(a2B_, XVB);                                                         \
    f32x4 aA0_ = __builtin_amdgcn_mfma_f32_16x16x32_bf16(a2A_.v, b2f[0], z, 0, 0, 0); \
    f32x4 aA1_ = __builtin_amdgcn_mfma_f32_16x16x32_bf16(a2A_.v, b2f[1], z, 0, 0, 0); \
    f32x4 aB0_ = __builtin_amdgcn_mfma_f32_16x16x32_bf16(a2B_.v, b2f[0], z, 0, 0, 0); \
    f32x4 aB1_ = __builtin_amdgcn_mfma_f32_16x16x32_bf16(a2B_.v, b2f[1], z, 0, 0, 0); \
    if (!(FIRST)) {                                                            \
        const bf16x8 a1A_ = *(const bf16x8*)&hbuf[(P) ^ 1][l15     ][kbase];   \
        const bf16x8 a1B_ = *(const bf16x8*)&hbuf[(P) ^ 1][l15 + 16][kbase];   \
        aA0_ = __builtin_amdgcn_mfma_f32_16x16x32_bf16(a1A_, b1f[0], aA0_, 0, 0, 0); \
        aA1_ = __builtin_amdgcn_mfma_f32_16x16x32_bf16(a1A_, b1f[1], aA1_, 0, 0, 0); \
        aB0_ = __builtin_amdgcn_mfma_f32_16x16x32_bf16(a1B_, b1f[0], aB0_, 0, 0, 0); \
        aB1_ = __builtin_amdgcn_mfma_f32_16x16x32_bf16(a1B_, b1f[1], aB1_, 0, 0, 0); \
    }                                                                          \
    float hA0_, hA1_, hB0_, hB1_;                                              \
    GUPD(aA0_, aA1_, cA0, cA1, hA0_, hA1_);                                    \
    GUPD(aB0_, aB1_, cB0, cB1, hB0_, hB1_);                                    \
    if (!(LAST)) {                                                             \
        hbuf[P][urow         ][j] = (__bf16)hA0_;                              \
        hbuf[P][urow + 1     ][j] = (__bf16)hA1_;                              \
        hbuf[P][urow + 16    ][j] = (__bf16)hB0_;                              \
        hbuf[P][urow + 17    ][j] = (__bf16)hB1_;                              \
    } else {                                                                   \
        fbuf[urow     ][j] = hA0_;                                             \
        fbuf[urow + 1 ][j] = hA1_;                                             \
        fbuf[urow + 16][j] = hB0_;                                             \
        fbuf[urow + 17][j] = hB1_;                                             \
    }                                                                          \
    __syncthreads();                                                           \
} while (0)

    // t = 0 (no h yet)
    SLOT(xqA.x, xqB.x, 0, true, false);

    // t = 1 .. 124, four steps per iteration (parities static)
    #pragma unroll 1
    for (int t = 1; t < 125; t += 4) {
        SLOT(xqA.y, xqB.y, 1, false, false);        // t
        SLOT(xqA.z, xqB.z, 0, false, false);        // t+1
        SLOT(xqA.w, xqB.w, 1, false, false);        // t+2
        xqA = *(const int4*)(xrowA + t + 3);        // words t+3 .. t+6
        xqB = *(const int4*)(xrowB + t + 3);
        SLOT(xqA.x, xqB.x, 0, false, false);        // t+3
    }

    // t = 125, 126, 127
    SLOT(xqA.y, xqB.y, 1, false, false);
    SLOT(xqA.z, xqB.z, 0, false, false);
    SLOT(xqA.w, xqB.w, 1, false, true);             // h -> fbuf (f32)

#undef SLOT
#undef GUPD
#undef ONEHOT

    // ---- FC epilogue: out[b] = h_last[b] @ fc_w^T + fc_b ----
    if (tid < 32) {
        float o0 = fc_b[0], o1 = fc_b[1];
        #pragma unroll
        for (int jj = 0; jj < HDIM; ++jj) {
            const float h = fbuf[tid][jj];
            o0 += fc_w[jj]        * h;
            o1 += fc_w[HDIM + jj] * h;
        }
        float2 res;
        res.x = o0; res.y = o1;
        *(float2*)&out[(row0 + tid) * 2] = res;
    }
}

extern "C" void kernel_launch(void* const* d_in, const int* in_sizes, int n_in,
                              void* d_out, int out_size, void* d_ws, size_t ws_size,
                              hipStream_t stream) {
    const int*   x    = (const int*)  d_in[0];
    const float* emb  = (const float*)d_in[1];
    const float* W_ih = (const float*)d_in[2];
    const float* W_hh = (const float*)d_in[3];
    const float* b_ih = (const float*)d_in[4];
    const float* b_hh = (const float*)d_in[5];
    const float* fc_w = (const float*)d_in[6];
    const float* fc_b = (const float*)d_in[7];
    float* out = (float*)d_out;

    const int B    = in_sizes[0] / TLEN;   // 16384
    const int nblk = B / 32;               // 512 blocks x 4 waves, 2 blocks/CU

    lstm_fused<<<nblk, 256, 0, stream>>>(x, emb, W_ih, W_hh, b_ih, b_hh, fc_w, fc_b, out);
}

// Round 7
// 118.383 us; speedup vs baseline: 1.2170x; 1.0197x over previous
//
#include <hip/hip_runtime.h>
#include <hip/hip_bf16.h>

typedef __bf16 bf16x8 __attribute__((ext_vector_type(8)));
typedef float  f32x4  __attribute__((ext_vector_type(4)));

#define VOCAB 24
#define EDIM  16
#define HDIM  32
#define TLEN  128

union A2U { int4 w; bf16x8 v; };

__device__ __forceinline__ float xor8f(float v) {
    // lane <- lane^8 within each 16-lane row (row_ror:8; VALU DPP, no LDS)
    int r = __builtin_amdgcn_update_dpp(0, __float_as_int(v), 0x128, 0xF, 0xF, true);
    return __int_as_float(r);
}
// B-matrices pre-scaled by -log2(e) (sigmoid cols) / -2*log2(e) (tanh cols):
__device__ __forceinline__ float rsig(float a) {   // sigmoid from scaled acc
    return __builtin_amdgcn_rcpf(1.0f + __builtin_amdgcn_exp2f(a));
}
__device__ __forceinline__ float fast_tanh(float x) {
    float t = __builtin_amdgcn_exp2f(x * -2.88539008f);
    return fmaf(2.0f, __builtin_amdgcn_rcpf(1.0f + t), -1.0f);
}

// Block = 4 waves, TWO independent 16-row groups (A rows 0-15, B rows 16-31).
// Wave w owns hidden j in [8w,8w+8) for both groups. Permuted-column tiles:
// tile p, col n -> gate q = 2p+(n>>3), hidden j = 8w+(n&7); tile0={i|f},
// tile1={g|o}. Gate sharing lane<->lane^8 via DPP row_ror:8.
// Software pipeline: next step's one-hot MFMAs (gates_x, accum p*) are issued
// BEFORE the barrier; post-barrier path is ds_read h -> 4 h-MFMA -> update.
// Tokens prefetched one 4-step iteration ahead.
__global__ __launch_bounds__(256, 2) void lstm_fused(
    const int*   __restrict__ x,     // [B][128]
    const float* __restrict__ emb,   // [24][16]
    const float* __restrict__ W_ih,  // [128][16]
    const float* __restrict__ W_hh,  // [128][32]
    const float* __restrict__ b_ih,  // [128]
    const float* __restrict__ b_hh,  // [128]
    const float* __restrict__ fc_w,  // [2][32]
    const float* __restrict__ fc_b,  // [2]
    float*       __restrict__ out)   // [B][2]
{
    __shared__ __align__(16) __bf16 hbuf[2][32][40];  // h dbuf; rows 0-15=A, 16-31=B
    __shared__ __align__(16) float  fbuf[32][33];     // final h (f32) for FC

    const int tid   = threadIdx.x;
    const int wid   = tid >> 6;
    const int lane  = tid & 63;
    const int l15   = lane & 15;
    const int hi    = lane >> 4;
    const int kbase = hi * 8;
    const int kh    = hi * 4;            // packed-word index base
    const int row0  = blockIdx.x * 32;
    const bool lowj = (l15 < 8);
    const int  j    = wid * 8 + (l15 & 7);

    // ---- B-fragments (permuted gate columns), pre-scaled, registers ----
    bf16x8 b1f[2];  // scale * W_hh^T
    bf16x8 b2f[2];  // scale * (emb[v].W_ih[gcol] + b_ih+b_hh)
    #pragma unroll
    for (int p = 0; p < 2; ++p) {
        const int q    = 2 * p + (l15 >> 3);
        const int gcol = q * 32 + j;
        const float scale = (q == 2) ? -2.88539008f : -1.44269504f;
        const float* wrow = W_hh + gcol * HDIM;
        #pragma unroll
        for (int i = 0; i < 8; ++i)
            b1f[p][i] = (__bf16)(scale * wrow[kbase + i]);
        const float bias = b_ih[gcol] + b_hh[gcol];
        const float* wi = W_ih + gcol * EDIM;
        #pragma unroll
        for (int i = 0; i < 8; ++i) {
            const int v = kbase + i;
            float s = 0.0f;
            if (v < VOCAB) {
                s = bias;
                #pragma unroll
                for (int e = 0; e < EDIM; ++e)
                    s += emb[v * EDIM + e] * wi[e];
            }
            b2f[p][i] = (__bf16)(scale * s);
        }
    }

    const float a1c  = lowj ?  2.0f : 1.0f;   // tile1: g->tanh, o->sigmoid
    const float b1c  = lowj ? -1.0f : 0.0f;
    const int   urow = 4 * hi + (lowj ? 0 : 2);

    float cA0 = 0.0f, cA1 = 0.0f, cB0 = 0.0f, cB1 = 0.0f;
    const int* xrowA = x + (row0 + l15) * TLEN;
    const int* xrowB = xrowA + 16 * TLEN;
    const f32x4 z = {0.f, 0.f, 0.f, 0.f};

    f32x4 pA0, pA1, pB0, pB1;   // pre-computed gates_x accumulators (next step)

#define ONEHOT(DST, XV) do {                                                   \
    const int xv_   = (XV);                                                    \
    const int hotw_ = 0x3F80 << ((xv_ & 1) << 4);                              \
    const int hoth_ = xv_ >> 1;                                                \
    DST.w.x = (hoth_ == kh + 0) ? hotw_ : 0;                                   \
    DST.w.y = (hoth_ == kh + 1) ? hotw_ : 0;                                   \
    DST.w.z = (hoth_ == kh + 2) ? hotw_ : 0;                                   \
    DST.w.w = (hoth_ == kh + 3) ? hotw_ : 0;                                   \
} while (0)

#define PRECOMP(XVA, XVB) do {                                                 \
    A2U a2A_, a2B_;                                                            \
    ONEHOT(a2A_, XVA);                                                         \
    ONEHOT(a2B_, XVB);                                                         \
    pA0 = __builtin_amdgcn_mfma_f32_16x16x32_bf16(a2A_.v, b2f[0], z, 0, 0, 0); \
    pA1 = __builtin_amdgcn_mfma_f32_16x16x32_bf16(a2A_.v, b2f[1], z, 0, 0, 0); \
    pB0 = __builtin_amdgcn_mfma_f32_16x16x32_bf16(a2B_.v, b2f[0], z, 0, 0, 0); \
    pB1 = __builtin_amdgcn_mfma_f32_16x16x32_bf16(a2B_.v, b2f[1], z, 0, 0, 0); \
} while (0)

#define GUPD(A0, A1, C0, C1, HV0, HV1) do {                                    \
    const float s00_ = rsig(A0[0]), s01_ = rsig(A0[1]);                        \
    const float s02_ = rsig(A0[2]), s03_ = rsig(A0[3]);                        \
    const float s10_ = fmaf(a1c, rsig(A1[0]), b1c);                            \
    const float s11_ = fmaf(a1c, rsig(A1[1]), b1c);                            \
    const float s12_ = fmaf(a1c, rsig(A1[2]), b1c);                            \
    const float s13_ = fmaf(a1c, rsig(A1[3]), b1c);                            \
    const float x00_ = xor8f(s00_), x01_ = xor8f(s01_);                        \
    const float x02_ = xor8f(s02_), x03_ = xor8f(s03_);                        \
    const float x10_ = xor8f(s10_), x11_ = xor8f(s11_);                        \
    const float x12_ = xor8f(s12_), x13_ = xor8f(s13_);                        \
    const float iv0_ = lowj ? s00_ : x02_;                                     \
    const float fv0_ = lowj ? x00_ : s02_;                                     \
    const float gv0_ = lowj ? s10_ : x12_;                                     \
    const float ov0_ = lowj ? x10_ : s12_;                                     \
    C0 = fmaf(fv0_, C0, iv0_ * gv0_);                                          \
    HV0 = ov0_ * fast_tanh(C0);                                                \
    const float iv1_ = lowj ? s01_ : x03_;                                     \
    const float fv1_ = lowj ? x01_ : s03_;                                     \
    const float gv1_ = lowj ? s11_ : x13_;                                     \
    const float ov1_ = lowj ? x11_ : s13_;                                     \
    C1 = fmaf(fv1_, C1, iv1_ * gv1_);                                          \
    HV1 = ov1_ * fast_tanh(C1);                                                \
} while (0)

// One timestep. P = t&1 (compile-time). On entry p* hold this step's gates_x.
// Before exiting (non-LAST) p* are refilled for the NEXT step (pre-barrier).
#define SLOT(P, FIRST, LAST, XVNA, XVNB) do {                                  \
    f32x4 aA0_, aA1_, aB0_, aB1_;                                              \
    if (FIRST) {                                                               \
        aA0_ = pA0; aA1_ = pA1; aB0_ = pB0; aB1_ = pB1;                        \
    } else {                                                                   \
        __syncthreads();                                                       \
        const bf16x8 a1A_ = *(const bf16x8*)&hbuf[(P) ^ 1][l15     ][kbase];   \
        const bf16x8 a1B_ = *(const bf16x8*)&hbuf[(P) ^ 1][l15 + 16][kbase];   \
        aA0_ = __builtin_amdgcn_mfma_f32_16x16x32_bf16(a1A_, b1f[0], pA0, 0, 0, 0); \
        aA1_ = __builtin_amdgcn_mfma_f32_16x16x32_bf16(a1A_, b1f[1], pA1, 0, 0, 0); \
        aB0_ = __builtin_amdgcn_mfma_f32_16x16x32_bf16(a1B_, b1f[0], pB0, 0, 0, 0); \
        aB1_ = __builtin_amdgcn_mfma_f32_16x16x32_bf16(a1B_, b1f[1], pB1, 0, 0, 0); \
    }                                                                          \
    float hA0_, hA1_, hB0_, hB1_;                                              \
    GUPD(aA0_, aA1_, cA0, cA1, hA0_, hA1_);                                    \
    GUPD(aB0_, aB1_, cB0, cB1, hB0_, hB1_);                                    \
    if (!(LAST)) {                                                             \
        hbuf[P][urow     ][j] = (__bf16)hA0_;                                  \
        hbuf[P][urow + 1 ][j] = (__bf16)hA1_;                                  \
        hbuf[P][urow + 16][j] = (__bf16)hB0_;                                  \
        hbuf[P][urow + 17][j] = (__bf16)hB1_;                                  \
        PRECOMP(XVNA, XVNB);                                                   \
    } else {                                                                   \
        fbuf[urow     ][j] = hA0_;                                             \
        fbuf[urow + 1 ][j] = hA1_;                                             \
        fbuf[urow + 16][j] = hB0_;                                             \
        fbuf[urow + 17][j] = hB1_;                                             \
    }                                                                          \
} while (0)

    // ---- prologue: tokens 0-3, gates_x for t=0; prefetch tokens 4-7 ----
    int4 q0A = *(const int4*)xrowA;
    int4 q0B = *(const int4*)xrowB;
    int4 xqA = *(const int4*)(xrowA + 4);
    int4 xqB = *(const int4*)(xrowB + 4);
    PRECOMP(q0A.x, q0B.x);

    // peeled t = 0,1,2
    SLOT(0, true,  false, q0A.y, q0B.y);
    SLOT(1, false, false, q0A.z, q0B.z);
    SLOT(0, false, false, q0A.w, q0B.w);

    // main: t = 3 .. 122. Entering with xq = tokens[t+1 .. t+4];
    // prefetch tokens[t+5 .. t+8] at iteration top.
    #pragma unroll 1
    for (int t = 3; t < 123; t += 4) {
        const int4 nA = *(const int4*)(xrowA + t + 5);
        const int4 nB = *(const int4*)(xrowB + t + 5);
        SLOT(1, false, false, xqA.x, xqB.x);   // t
        SLOT(0, false, false, xqA.y, xqB.y);   // t+1
        SLOT(1, false, false, xqA.z, xqB.z);   // t+2
        SLOT(0, false, false, xqA.w, xqB.w);   // t+3
        xqA = nA; xqB = nB;
    }

    // tail: t = 123..127 (xq = tokens[124..127])
    SLOT(1, false, false, xqA.x, xqB.x);       // 123
    SLOT(0, false, false, xqA.y, xqB.y);       // 124
    SLOT(1, false, false, xqA.z, xqB.z);       // 125
    SLOT(0, false, false, xqA.w, xqB.w);       // 126
    SLOT(1, false, true,  0,     0);           // 127 -> fbuf

#undef SLOT
#undef GUPD
#undef PRECOMP
#undef ONEHOT

    __syncthreads();

    // ---- FC epilogue: out[b] = h_last[b] @ fc_w^T + fc_b ----
    if (tid < 32) {
        float o0 = fc_b[0], o1 = fc_b[1];
        #pragma unroll
        for (int jj = 0; jj < HDIM; ++jj) {
            const float h = fbuf[tid][jj];
            o0 += fc_w[jj]        * h;
            o1 += fc_w[HDIM + jj] * h;
        }
        float2 res;
        res.x = o0; res.y = o1;
        *(float2*)&out[(row0 + tid) * 2] = res;
    }
}

extern "C" void kernel_launch(void* const* d_in, const int* in_sizes, int n_in,
                              void* d_out, int out_size, void* d_ws, size_t ws_size,
                              hipStream_t stream) {
    const int*   x    = (const int*)  d_in[0];
    const float* emb  = (const float*)d_in[1];
    const float* W_ih = (const float*)d_in[2];
    const float* W_hh = (const float*)d_in[3];
    const float* b_ih = (const float*)d_in[4];
    const float* b_hh = (const float*)d_in[5];
    const float* fc_w = (const float*)d_in[6];
    const float* fc_b = (const float*)d_in[7];
    float* out = (float*)d_out;

    const int B    = in_sizes[0] / TLEN;   // 16384
    const int nblk = B / 32;               // 512 blocks x 4 waves, 2 blocks/CU

    lstm_fused<<<nblk, 256, 0, stream>>>(x, emb, W_ih, W_hh, b_ih, b_hh, fc_w, fc_b, out);
}

// Round 8
// 115.742 us; speedup vs baseline: 1.2448x; 1.0228x over previous
//
#include <hip/hip_runtime.h>
#include <hip/hip_bf16.h>

typedef __bf16 bf16x8 __attribute__((ext_vector_type(8)));
typedef float  f32x4  __attribute__((ext_vector_type(4)));

#define VOCAB 24
#define EDIM  16
#define HDIM  32
#define TLEN  128

union A2U { int4 w; bf16x8 v; };

__device__ __forceinline__ float xor8f(float v) {
    // lane <- lane^8 within each 16-lane row (row_ror:8; VALU DPP, no LDS)
    int r = __builtin_amdgcn_update_dpp(0, __float_as_int(v), 0x128, 0xF, 0xF, true);
    return __int_as_float(r);
}
// B-matrices pre-scaled by -log2(e) (sigmoid cols) / -2*log2(e) (tanh cols):
__device__ __forceinline__ float rsig(float a) {   // sigmoid from scaled acc
    return __builtin_amdgcn_rcpf(1.0f + __builtin_amdgcn_exp2f(a));
}
__device__ __forceinline__ float fast_tanh(float x) {
    float t = __builtin_amdgcn_exp2f(x * -2.88539008f);
    return fmaf(2.0f, __builtin_amdgcn_rcpf(1.0f + t), -1.0f);
}

// LDS-only sync: waits this wave's ds ops, then barrier. Does NOT drain
// vmcnt -> global token prefetches stay in flight across steps (unlike
// __syncthreads, whose vmcnt(0) drain stalled every 4th step on L2 latency).
__device__ __forceinline__ void block_sync_lds() {
    asm volatile("s_waitcnt lgkmcnt(0)" ::: "memory");
    __builtin_amdgcn_s_barrier();
    asm volatile("" ::: "memory");
}

// Block = 4 waves, TWO independent 16-row groups (A rows 0-15, B rows 16-31).
// Wave w owns hidden j in [8w,8w+8) for both groups. Permuted-column tiles:
// tile p, col n -> gate q = 2p+(n>>3), hidden j = 8w+(n&7); tile0={i|f},
// tile1={g|o}. Gate sharing lane<->lane^8 via DPP row_ror:8.
// Slot order: barrier -> issue h ds_reads -> one-hot + gates_x MFMAs (filler
// covering LDS latency) -> h-MFMAs -> pointwise update -> h writes.
__global__ __launch_bounds__(256, 2) void lstm_fused(
    const int*   __restrict__ x,     // [B][128]
    const float* __restrict__ emb,   // [24][16]
    const float* __restrict__ W_ih,  // [128][16]
    const float* __restrict__ W_hh,  // [128][32]
    const float* __restrict__ b_ih,  // [128]
    const float* __restrict__ b_hh,  // [128]
    const float* __restrict__ fc_w,  // [2][32]
    const float* __restrict__ fc_b,  // [2]
    float*       __restrict__ out)   // [B][2]
{
    __shared__ __align__(16) __bf16 hbuf[2][32][40];  // h dbuf; rows 0-15=A, 16-31=B
    __shared__ __align__(16) float  fbuf[32][33];     // final h (f32) for FC

    const int tid   = threadIdx.x;
    const int wid   = tid >> 6;
    const int lane  = tid & 63;
    const int l15   = lane & 15;
    const int hi    = lane >> 4;
    const int kbase = hi * 8;
    const int kh    = hi * 4;            // packed-word index base
    const int row0  = blockIdx.x * 32;
    const bool lowj = (l15 < 8);
    const int  j    = wid * 8 + (l15 & 7);

    // ---- B-fragments (permuted gate columns), pre-scaled, registers ----
    bf16x8 b1f[2];  // scale * W_hh^T
    bf16x8 b2f[2];  // scale * (emb[v].W_ih[gcol] + b_ih+b_hh)
    #pragma unroll
    for (int p = 0; p < 2; ++p) {
        const int q    = 2 * p + (l15 >> 3);
        const int gcol = q * 32 + j;
        const float scale = (q == 2) ? -2.88539008f : -1.44269504f;
        const float* wrow = W_hh + gcol * HDIM;
        #pragma unroll
        for (int i = 0; i < 8; ++i)
            b1f[p][i] = (__bf16)(scale * wrow[kbase + i]);
        const float bias = b_ih[gcol] + b_hh[gcol];
        const float* wi = W_ih + gcol * EDIM;
        #pragma unroll
        for (int i = 0; i < 8; ++i) {
            const int v = kbase + i;
            float s = 0.0f;
            if (v < VOCAB) {
                s = bias;
                #pragma unroll
                for (int e = 0; e < EDIM; ++e)
                    s += emb[v * EDIM + e] * wi[e];
            }
            b2f[p][i] = (__bf16)(scale * s);
        }
    }

    const float a1c  = lowj ?  2.0f : 1.0f;   // tile1: g->tanh, o->sigmoid
    const float b1c  = lowj ? -1.0f : 0.0f;
    const int   urow = 4 * hi + (lowj ? 0 : 2);

    float cA0 = 0.0f, cA1 = 0.0f, cB0 = 0.0f, cB1 = 0.0f;
    const int* xrowA = x + (row0 + l15) * TLEN;
    const int* xrowB = xrowA + 16 * TLEN;
    const f32x4 z = {0.f, 0.f, 0.f, 0.f};

#define ONEHOT(DST, XV) do {                                                   \
    const int xv_   = (XV);                                                    \
    const int hotw_ = 0x3F80 << ((xv_ & 1) << 4);                              \
    const int hoth_ = xv_ >> 1;                                                \
    DST.w.x = (hoth_ == kh + 0) ? hotw_ : 0;                                   \
    DST.w.y = (hoth_ == kh + 1) ? hotw_ : 0;                                   \
    DST.w.z = (hoth_ == kh + 2) ? hotw_ : 0;                                   \
    DST.w.w = (hoth_ == kh + 3) ? hotw_ : 0;                                   \
} while (0)

#define GUPD(A0, A1, C0, C1, HV0, HV1) do {                                    \
    const float s00_ = rsig(A0[0]), s01_ = rsig(A0[1]);                        \
    const float s02_ = rsig(A0[2]), s03_ = rsig(A0[3]);                        \
    const float s10_ = fmaf(a1c, rsig(A1[0]), b1c);                            \
    const float s11_ = fmaf(a1c, rsig(A1[1]), b1c);                            \
    const float s12_ = fmaf(a1c, rsig(A1[2]), b1c);                            \
    const float s13_ = fmaf(a1c, rsig(A1[3]), b1c);                            \
    const float x00_ = xor8f(s00_), x01_ = xor8f(s01_);                        \
    const float x02_ = xor8f(s02_), x03_ = xor8f(s03_);                        \
    const float x10_ = xor8f(s10_), x11_ = xor8f(s11_);                        \
    const float x12_ = xor8f(s12_), x13_ = xor8f(s13_);                        \
    const float iv0_ = lowj ? s00_ : x02_;                                     \
    const float fv0_ = lowj ? x00_ : s02_;                                     \
    const float gv0_ = lowj ? s10_ : x12_;                                     \
    const float ov0_ = lowj ? x10_ : s12_;                                     \
    C0 = fmaf(fv0_, C0, iv0_ * gv0_);                                          \
    HV0 = ov0_ * fast_tanh(C0);                                                \
    const float iv1_ = lowj ? s01_ : x03_;                                     \
    const float fv1_ = lowj ? x01_ : s03_;                                     \
    const float gv1_ = lowj ? s11_ : x13_;                                     \
    const float ov1_ = lowj ? x11_ : s13_;                                     \
    C1 = fmaf(fv1_, C1, iv1_ * gv1_);                                          \
    HV1 = ov1_ * fast_tanh(C1);                                                \
} while (0)

// One timestep, both groups. P = t&1 (compile-time). XVA/XVB = THIS step's
// tokens. Order: barrier, h-reads, one-hot+gates_x MFMAs (latency filler),
// h-MFMAs, update, writes.
#define SLOT(P, FIRST, LAST, XVA, XVB) do {                                    \
    bf16x8 a1A_, a1B_;                                                         \
    if (!(FIRST)) {                                                            \
        block_sync_lds();                                                      \
        a1A_ = *(const bf16x8*)&hbuf[(P) ^ 1][l15     ][kbase];                \
        a1B_ = *(const bf16x8*)&hbuf[(P) ^ 1][l15 + 16][kbase];                \
    }                                                                          \
    A2U a2A_, a2B_;                                                            \
    ONEHOT(a2A_, XVA);                                                         \
    ONEHOT(a2B_, XVB);                                                         \
    f32x4 aA0_ = __builtin_amdgcn_mfma_f32_16x16x32_bf16(a2A_.v, b2f[0], z, 0, 0, 0); \
    f32x4 aA1_ = __builtin_amdgcn_mfma_f32_16x16x32_bf16(a2A_.v, b2f[1], z, 0, 0, 0); \
    f32x4 aB0_ = __builtin_amdgcn_mfma_f32_16x16x32_bf16(a2B_.v, b2f[0], z, 0, 0, 0); \
    f32x4 aB1_ = __builtin_amdgcn_mfma_f32_16x16x32_bf16(a2B_.v, b2f[1], z, 0, 0, 0); \
    if (!(FIRST)) {                                                            \
        aA0_ = __builtin_amdgcn_mfma_f32_16x16x32_bf16(a1A_, b1f[0], aA0_, 0, 0, 0); \
        aA1_ = __builtin_amdgcn_mfma_f32_16x16x32_bf16(a1A_, b1f[1], aA1_, 0, 0, 0); \
        aB0_ = __builtin_amdgcn_mfma_f32_16x16x32_bf16(a1B_, b1f[0], aB0_, 0, 0, 0); \
        aB1_ = __builtin_amdgcn_mfma_f32_16x16x32_bf16(a1B_, b1f[1], aB1_, 0, 0, 0); \
    }                                                                          \
    float hA0_, hA1_, hB0_, hB1_;                                              \
    GUPD(aA0_, aA1_, cA0, cA1, hA0_, hA1_);                                    \
    GUPD(aB0_, aB1_, cB0, cB1, hB0_, hB1_);                                    \
    if (!(LAST)) {                                                             \
        hbuf[P][urow     ][j] = (__bf16)hA0_;                                  \
        hbuf[P][urow + 1 ][j] = (__bf16)hA1_;                                  \
        hbuf[P][urow + 16][j] = (__bf16)hB0_;                                  \
        hbuf[P][urow + 17][j] = (__bf16)hB1_;                                  \
    } else {                                                                   \
        fbuf[urow     ][j] = hA0_;                                             \
        fbuf[urow + 1 ][j] = hA1_;                                             \
        fbuf[urow + 16][j] = hB0_;                                             \
        fbuf[urow + 17][j] = hB1_;                                             \
    }                                                                          \
} while (0)

    // ---- prologue: tokens 0-3 and 4-7 ----
    int4 q0A = *(const int4*)xrowA;
    int4 q0B = *(const int4*)xrowB;
    int4 xqA = *(const int4*)(xrowA + 4);
    int4 xqB = *(const int4*)(xrowB + 4);

    // t = 0..3
    SLOT(0, true,  false, q0A.x, q0B.x);
    SLOT(1, false, false, q0A.y, q0B.y);
    SLOT(0, false, false, q0A.z, q0B.z);
    SLOT(1, false, false, q0A.w, q0B.w);

    // main: t = 4 .. 123. Entering with xq = tokens[t..t+3];
    // prefetch tokens[t+4..t+7] at iteration top (stays in flight across
    // the lgkm-only barriers).
    #pragma unroll 1
    for (int t = 4; t < 124; t += 4) {
        const int4 nA = *(const int4*)(xrowA + t + 4);
        const int4 nB = *(const int4*)(xrowB + t + 4);
        SLOT(0, false, false, xqA.x, xqB.x);   // t
        SLOT(1, false, false, xqA.y, xqB.y);   // t+1
        SLOT(0, false, false, xqA.z, xqB.z);   // t+2
        SLOT(1, false, false, xqA.w, xqB.w);   // t+3
        xqA = nA; xqB = nB;
    }

    // tail: t = 124..127
    SLOT(0, false, false, xqA.x, xqB.x);       // 124
    SLOT(1, false, false, xqA.y, xqB.y);       // 125
    SLOT(0, false, false, xqA.z, xqB.z);       // 126
    SLOT(1, false, true,  xqA.w, xqB.w);       // 127 -> fbuf

#undef SLOT
#undef GUPD
#undef ONEHOT

    __syncthreads();   // final: fbuf visible (full drain fine here, once)

    // ---- FC epilogue: out[b] = h_last[b] @ fc_w^T + fc_b ----
    if (tid < 32) {
        float o0 = fc_b[0], o1 = fc_b[1];
        #pragma unroll
        for (int jj = 0; jj < HDIM; ++jj) {
            const float h = fbuf[tid][jj];
            o0 += fc_w[jj]        * h;
            o1 += fc_w[HDIM + jj] * h;
        }
        float2 res;
        res.x = o0; res.y = o1;
        *(float2*)&out[(row0 + tid) * 2] = res;
    }
}

extern "C" void kernel_launch(void* const* d_in, const int* in_sizes, int n_in,
                              void* d_out, int out_size, void* d_ws, size_t ws_size,
                              hipStream_t stream) {
    const int*   x    = (const int*)  d_in[0];
    const float* emb  = (const float*)d_in[1];
    const float* W_ih = (const float*)d_in[2];
    const float* W_hh = (const float*)d_in[3];
    const float* b_ih = (const float*)d_in[4];
    const float* b_hh = (const float*)d_in[5];
    const float* fc_w = (const float*)d_in[6];
    const float* fc_b = (const float*)d_in[7];
    float* out = (float*)d_out;

    const int B    = in_sizes[0] / TLEN;   // 16384
    const int nblk = B / 32;               // 512 blocks x 4 waves, 2 blocks/CU

    lstm_fused<<<nblk, 256, 0, stream>>>(x, emb, W_ih, W_hh, b_ih, b_hh, fc_w, fc_b, out);
}